// Round 1
// baseline (701.903 us; speedup 1.0000x reference)
//
#include <hip/hip_runtime.h>

#define NB     262144          // batch samples
#define NNODE  (NB * 4)        // total label nodes
#define EMB_ELEMS ((size_t)NNODE * 64)

// ---------------------------------------------------------------------------
// Kernel 1: per-sample cosine-similarity adjacency, OR-reduced into one mask.
// Bit p encodes pair (i<j) in order (0,1),(0,2),(0,3),(1,2),(1,3),(2,3).
// ---------------------------------------------------------------------------
__global__ __launch_bounds__(256) void adj_kernel(const float* __restrict__ x,
                                                  unsigned int* __restrict__ mask_out) {
    __shared__ unsigned int smask;
    if (threadIdx.x == 0) smask = 0u;
    __syncthreads();

    unsigned int m = 0u;
    int s = blockIdx.x * 256 + threadIdx.x;
    if (s < NB) {
        const float* xs = x + (size_t)s * 16;
        float v[4][4], inv[4];
#pragma unroll
        for (int c = 0; c < 4; ++c) {
            float4 q = *reinterpret_cast<const float4*>(xs + c * 4);
            v[c][0] = q.x; v[c][1] = q.y; v[c][2] = q.z; v[c][3] = q.w;
            float nn = sqrtf(q.x * q.x + q.y * q.y + q.z * q.z + q.w * q.w);
            inv[c] = 1.0f / fmaxf(nn, 1e-8f);
        }
        int bit = 0;
#pragma unroll
        for (int i = 0; i < 4; ++i) {
#pragma unroll
            for (int j = i + 1; j < 4; ++j) {
                float d = v[i][0] * v[j][0] + v[i][1] * v[j][1] +
                          v[i][2] * v[j][2] + v[i][3] * v[j][3];
                if (d * inv[i] * inv[j] > 0.5f) m |= (1u << bit);
                ++bit;
            }
        }
    }
    atomicOr(&smask, m);
    __syncthreads();
    if (threadIdx.x == 0 && smask) atomicOr(mask_out, smask);
}

// ---------------------------------------------------------------------------
// Kernel 2: build Ahat = D^-1/2 (A+I) D^-1/2 from the 6-bit mask. One thread.
// ---------------------------------------------------------------------------
__global__ void ahat_kernel(const unsigned int* __restrict__ mask_in,
                            float* __restrict__ ahat) {
    if (threadIdx.x != 0 || blockIdx.x != 0) return;
    unsigned int m = *mask_in;
    float A[4][4];
    for (int i = 0; i < 4; ++i)
        for (int j = 0; j < 4; ++j) A[i][j] = (i == j) ? 1.f : 0.f;
    int bit = 0;
    for (int i = 0; i < 4; ++i)
        for (int j = i + 1; j < 4; ++j) {
            if ((m >> bit) & 1u) { A[i][j] = 1.f; A[j][i] = 1.f; }
            ++bit;
        }
    float dinv[4];
    for (int i = 0; i < 4; ++i) {
        float d = A[i][0] + A[i][1] + A[i][2] + A[i][3];
        dinv[i] = 1.0f / sqrtf(d);
    }
    for (int i = 0; i < 4; ++i)
        for (int j = 0; j < 4; ++j) ahat[i * 4 + j] = dinv[i] * A[i][j] * dinv[j];
}

// ---------------------------------------------------------------------------
// Kernel 3: fused MLP (4->128->64->64) + GCN (64->32->4).
// One thread per node; nodes of a sample sit in adjacent lanes (tid&3 = node),
// so Ahat mixing is done with 4 __shfl's. Weights staged in LDS, read at
// wave-uniform addresses (broadcast, conflict-free, b128-vectorizable).
// ---------------------------------------------------------------------------
__global__ __launch_bounds__(256) void mlp_gcn_kernel(
    const float* __restrict__ x,
    const float* __restrict__ W1, const float* __restrict__ b1,
    const float* __restrict__ W2, const float* __restrict__ b2,
    const float* __restrict__ W3, const float* __restrict__ b3,
    const float* __restrict__ Wg1, const float* __restrict__ bg1,
    const float* __restrict__ Wg2, const float* __restrict__ bg2,
    const float* __restrict__ ahat,
    float* __restrict__ emb_out, float* __restrict__ out_out)
{
    // ---- LDS weight staging (61.1 KB total) ----
    __shared__ float sW1t[128 * 4];   // transposed: [k][f] so one b128/k
    __shared__ float sb1[128];
    __shared__ float sW2[128 * 64];
    __shared__ float sb2[64];
    __shared__ float sW3[64 * 64];
    __shared__ float sb3[64];
    __shared__ float sWg1[64 * 32];
    __shared__ float sbg1[32];
    __shared__ float sWg2[32 * 4];
    __shared__ float sbg2[4];
    __shared__ float sAhat[16];

    const int tx = threadIdx.x;
    for (int i = tx; i < 512; i += 256) { int k = i >> 2, f = i & 3; sW1t[i] = W1[f * 128 + k]; }
    for (int i = tx; i < 128;  i += 256) sb1[i]  = b1[i];
    for (int i = tx; i < 8192; i += 256) sW2[i]  = W2[i];
    for (int i = tx; i < 64;   i += 256) sb2[i]  = b2[i];
    for (int i = tx; i < 4096; i += 256) sW3[i]  = W3[i];
    for (int i = tx; i < 64;   i += 256) sb3[i]  = b3[i];
    for (int i = tx; i < 2048; i += 256) sWg1[i] = Wg1[i];
    for (int i = tx; i < 32;   i += 256) sbg1[i] = bg1[i];
    for (int i = tx; i < 128;  i += 256) sWg2[i] = Wg2[i];
    for (int i = tx; i < 4;    i += 256) sbg2[i] = bg2[i];
    for (int i = tx; i < 16;   i += 256) sAhat[i] = ahat[i];
    __syncthreads();

    const int tid = blockIdx.x * 256 + tx;
    if (tid >= NNODE) return;

    const float4 xq = *reinterpret_cast<const float4*>(x + (size_t)tid * 4);

    // ---- layers 1+2 fused, k-outer streaming: acc[j] = b2[j] + sum_k relu(h1_k) W2[k,j]
    float acc[64];
#pragma unroll
    for (int j = 0; j < 64; ++j) acc[j] = sb2[j];

#pragma unroll 2
    for (int k = 0; k < 128; ++k) {
        float h1 = sb1[k];
        h1 = fmaf(xq.x, sW1t[k * 4 + 0], h1);
        h1 = fmaf(xq.y, sW1t[k * 4 + 1], h1);
        h1 = fmaf(xq.z, sW1t[k * 4 + 2], h1);
        h1 = fmaf(xq.w, sW1t[k * 4 + 3], h1);
        h1 = fmaxf(h1, 0.f);
        const float* w2row = &sW2[k * 64];
#pragma unroll
        for (int j = 0; j < 64; ++j) acc[j] = fmaf(h1, w2row[j], acc[j]);
    }
    // relu -> h2
#pragma unroll
    for (int j = 0; j < 64; ++j) acc[j] = fmaxf(acc[j], 0.f);

    // ---- layer 3 (emb = h2 @ W3 + b3) in 16-wide chunks; fold emb @ Wg1 into tt
    float tt[32];
#pragma unroll
    for (int e = 0; e < 32; ++e) tt[e] = 0.f;

    float* embp = emb_out + (size_t)tid * 64;
#pragma unroll 1
    for (int hc = 0; hc < 4; ++hc) {
        float e16[16];
#pragma unroll
        for (int h = 0; h < 16; ++h) e16[h] = sb3[hc * 16 + h];
#pragma unroll
        for (int j = 0; j < 64; ++j) {
            const float a = acc[j];
            const float* w3p = &sW3[j * 64 + hc * 16];
#pragma unroll
            for (int h = 0; h < 16; ++h) e16[h] = fmaf(a, w3p[h], e16[h]);
        }
        // write emb chunk (float4 x4)
        float4* ep = reinterpret_cast<float4*>(embp + hc * 16);
        ep[0] = make_float4(e16[0],  e16[1],  e16[2],  e16[3]);
        ep[1] = make_float4(e16[4],  e16[5],  e16[6],  e16[7]);
        ep[2] = make_float4(e16[8],  e16[9],  e16[10], e16[11]);
        ep[3] = make_float4(e16[12], e16[13], e16[14], e16[15]);
        // tt += e16 @ Wg1[chunk rows]
#pragma unroll
        for (int h = 0; h < 16; ++h) {
            const float a = e16[h];
            const float* wg1p = &sWg1[(hc * 16 + h) * 32];
#pragma unroll
            for (int e = 0; e < 32; ++e) tt[e] = fmaf(a, wg1p[e], tt[e]);
        }
    }

    // ---- GCN mixing: lanes 4s..4s+3 hold nodes 0..3 of sample s
    const int c = tid & 3;
    const float ar0 = sAhat[c * 4 + 0];
    const float ar1 = sAhat[c * 4 + 1];
    const float ar2 = sAhat[c * 4 + 2];
    const float ar3 = sAhat[c * 4 + 3];
    const int lbase = (tx & 63) & ~3;

    float g[32];
#pragma unroll
    for (int e = 0; e < 32; ++e) {
        float v0 = __shfl(tt[e], lbase + 0, 64);
        float v1 = __shfl(tt[e], lbase + 1, 64);
        float v2 = __shfl(tt[e], lbase + 2, 64);
        float v3 = __shfl(tt[e], lbase + 3, 64);
        float s = sbg1[e];
        s = fmaf(ar0, v0, s);
        s = fmaf(ar1, v1, s);
        s = fmaf(ar2, v2, s);
        s = fmaf(ar3, v3, s);
        g[e] = fmaxf(s, 0.f);
    }

    float uu[4];
#pragma unroll
    for (int o = 0; o < 4; ++o) {
        float s = 0.f;
#pragma unroll
        for (int e = 0; e < 32; ++e) s = fmaf(g[e], sWg2[e * 4 + o], s);
        uu[o] = s;
    }

    float ov[4];
#pragma unroll
    for (int o = 0; o < 4; ++o) {
        float v0 = __shfl(uu[o], lbase + 0, 64);
        float v1 = __shfl(uu[o], lbase + 1, 64);
        float v2 = __shfl(uu[o], lbase + 2, 64);
        float v3 = __shfl(uu[o], lbase + 3, 64);
        float s = sbg2[o];
        s = fmaf(ar0, v0, s);
        s = fmaf(ar1, v1, s);
        s = fmaf(ar2, v2, s);
        s = fmaf(ar3, v3, s);
        ov[o] = s;
    }
    *reinterpret_cast<float4*>(out_out + (size_t)tid * 4) =
        make_float4(ov[0], ov[1], ov[2], ov[3]);
}

// ---------------------------------------------------------------------------
extern "C" void kernel_launch(void* const* d_in, const int* in_sizes, int n_in,
                              void* d_out, int out_size, void* d_ws, size_t ws_size,
                              hipStream_t stream) {
    const float* x   = (const float*)d_in[0];
    const float* W1  = (const float*)d_in[1];
    const float* b1  = (const float*)d_in[2];
    const float* W2  = (const float*)d_in[3];
    const float* b2  = (const float*)d_in[4];
    const float* W3  = (const float*)d_in[5];
    const float* b3  = (const float*)d_in[6];
    const float* Wg1 = (const float*)d_in[7];
    const float* bg1 = (const float*)d_in[8];
    const float* Wg2 = (const float*)d_in[9];
    const float* bg2 = (const float*)d_in[10];

    unsigned int* ws_mask = (unsigned int*)d_ws;
    float* ahat = (float*)((char*)d_ws + 64);

    float* emb_out = (float*)d_out;
    float* out_out = emb_out + EMB_ELEMS;

    hipMemsetAsync(d_ws, 0, 4, stream);                       // zero the OR-mask
    adj_kernel<<<NB / 256, 256, 0, stream>>>(x, ws_mask);     // 1024 blocks
    ahat_kernel<<<1, 64, 0, stream>>>(ws_mask, ahat);
    mlp_gcn_kernel<<<NNODE / 256, 256, 0, stream>>>(          // 4096 blocks
        x, W1, b1, W2, b2, W3, b3, Wg1, bg1, Wg2, bg2, ahat, emb_out, out_out);
}

// Round 2
// 621.413 us; speedup vs baseline: 1.1295x; 1.1295x over previous
//
#include <hip/hip_runtime.h>

#define NB     262144          // batch samples
#define NNODE  (NB * 4)        // total label nodes
#define EMB_ELEMS ((size_t)NNODE * 64)

// ---------------------------------------------------------------------------
// Kernel 1: per-sample cosine-similarity adjacency, OR-reduced into one mask.
// ---------------------------------------------------------------------------
__global__ __launch_bounds__(256) void adj_kernel(const float* __restrict__ x,
                                                  unsigned int* __restrict__ mask_out) {
    __shared__ unsigned int smask;
    if (threadIdx.x == 0) smask = 0u;
    __syncthreads();

    unsigned int m = 0u;
    int s = blockIdx.x * 256 + threadIdx.x;
    if (s < NB) {
        const float* xs = x + (size_t)s * 16;
        float v[4][4], inv[4];
#pragma unroll
        for (int c = 0; c < 4; ++c) {
            float4 q = *reinterpret_cast<const float4*>(xs + c * 4);
            v[c][0] = q.x; v[c][1] = q.y; v[c][2] = q.z; v[c][3] = q.w;
            float nn = sqrtf(q.x * q.x + q.y * q.y + q.z * q.z + q.w * q.w);
            inv[c] = 1.0f / fmaxf(nn, 1e-8f);
        }
        int bit = 0;
#pragma unroll
        for (int i = 0; i < 4; ++i) {
#pragma unroll
            for (int j = i + 1; j < 4; ++j) {
                float d = v[i][0] * v[j][0] + v[i][1] * v[j][1] +
                          v[i][2] * v[j][2] + v[i][3] * v[j][3];
                if (d * inv[i] * inv[j] > 0.5f) m |= (1u << bit);
                ++bit;
            }
        }
    }
    atomicOr(&smask, m);
    __syncthreads();
    if (threadIdx.x == 0 && smask) atomicOr(mask_out, smask);
}

// ---------------------------------------------------------------------------
// Kernel 2: build Ahat from the 6-bit mask. One thread.
// ---------------------------------------------------------------------------
__global__ void ahat_kernel(const unsigned int* __restrict__ mask_in,
                            float* __restrict__ ahat) {
    if (threadIdx.x != 0 || blockIdx.x != 0) return;
    unsigned int m = *mask_in;
    float A[4][4];
    for (int i = 0; i < 4; ++i)
        for (int j = 0; j < 4; ++j) A[i][j] = (i == j) ? 1.f : 0.f;
    int bit = 0;
    for (int i = 0; i < 4; ++i)
        for (int j = i + 1; j < 4; ++j) {
            if ((m >> bit) & 1u) { A[i][j] = 1.f; A[j][i] = 1.f; }
            ++bit;
        }
    float dinv[4];
    for (int i = 0; i < 4; ++i) {
        float d = A[i][0] + A[i][1] + A[i][2] + A[i][3];
        dinv[i] = 1.0f / sqrtf(d);
    }
    for (int i = 0; i < 4; ++i)
        for (int j = 0; j < 4; ++j) ahat[i * 4 + j] = dinv[i] * A[i][j] * dinv[j];
}

// ---------------------------------------------------------------------------
// Kernel 2b: precompute W3g = W3 @ Wg1 [64x32], b3g = b3 @ Wg1 [32].
// ---------------------------------------------------------------------------
__global__ __launch_bounds__(256) void prep_kernel(
    const float* __restrict__ W3, const float* __restrict__ b3,
    const float* __restrict__ Wg1,
    float* __restrict__ W3g, float* __restrict__ b3g) {
    int t = threadIdx.x;
    for (int i = t; i < 64 * 32; i += 256) {
        int j = i >> 5, e = i & 31;
        float s = 0.f;
        for (int h = 0; h < 64; ++h) s = fmaf(W3[j * 64 + h], Wg1[h * 32 + e], s);
        W3g[i] = s;
    }
    if (t < 32) {
        float s = 0.f;
        for (int h = 0; h < 64; ++h) s = fmaf(b3[h], Wg1[h * 32 + t], s);
        b3g[t] = s;
    }
}

// ---------------------------------------------------------------------------
// Kernel 3: fused MLP (4->128->64->64) + GCN (64->32->4).
// One thread per node. NO LDS: weights are wave-uniform -> compiler
// scalarizes to s_load_* and v_fma takes the weight as the SGPR operand.
// ---------------------------------------------------------------------------
__global__ __launch_bounds__(256, 3) void mlp_gcn_kernel(
    const float* __restrict__ x,
    const float* __restrict__ W1, const float* __restrict__ b1,
    const float* __restrict__ W2, const float* __restrict__ b2,
    const float* __restrict__ W3, const float* __restrict__ b3,
    const float* __restrict__ ahat,
    const float* __restrict__ W3g, const float* __restrict__ b3g,
    const float* __restrict__ Wg2, const float* __restrict__ bg2,
    const float* __restrict__ bg1,
    float* __restrict__ emb_out, float* __restrict__ out_out)
{
    const int tx = threadIdx.x;
    const int tid = blockIdx.x * 256 + tx;

    const float4 xq = *reinterpret_cast<const float4*>(x + (size_t)tid * 4);

    // ---- layers 1+2 fused: acc[j] = b2[j] + sum_k relu(h1_k) W2[k,j]
    float acc[64];
#pragma unroll
    for (int j = 0; j < 64; ++j) acc[j] = b2[j];

#pragma unroll 2
    for (int k = 0; k < 128; ++k) {
        float h1 = b1[k];
        h1 = fmaf(xq.x, W1[0 * 128 + k], h1);
        h1 = fmaf(xq.y, W1[1 * 128 + k], h1);
        h1 = fmaf(xq.z, W1[2 * 128 + k], h1);
        h1 = fmaf(xq.w, W1[3 * 128 + k], h1);
        h1 = fmaxf(h1, 0.f);
        const float* w2row = W2 + k * 64;
#pragma unroll
        for (int j = 0; j < 64; ++j) acc[j] = fmaf(h1, w2row[j], acc[j]);
    }
#pragma unroll
    for (int j = 0; j < 64; ++j) acc[j] = fmaxf(acc[j], 0.f);   // h2

    // ---- tt = h2 @ (W3@Wg1) + b3@Wg1
    float tt[32];
#pragma unroll
    for (int e = 0; e < 32; ++e) tt[e] = b3g[e];
#pragma unroll 2
    for (int j = 0; j < 64; ++j) {
        const float a = acc[j];
        const float* p = W3g + j * 32;
#pragma unroll
        for (int e = 0; e < 32; ++e) tt[e] = fmaf(a, p[e], tt[e]);
    }

    // ---- emb = h2 @ W3 + b3, 16-wide chunks, stores back-to-back
    float* embp = emb_out + (size_t)tid * 64;
#pragma unroll 1
    for (int hc = 0; hc < 4; ++hc) {
        float e16[16];
#pragma unroll
        for (int h = 0; h < 16; ++h) e16[h] = b3[hc * 16 + h];
#pragma unroll
        for (int j = 0; j < 64; ++j) {
            const float a = acc[j];
            const float* w3p = W3 + j * 64 + hc * 16;
#pragma unroll
            for (int h = 0; h < 16; ++h) e16[h] = fmaf(a, w3p[h], e16[h]);
        }
        float4* ep = reinterpret_cast<float4*>(embp + hc * 16);
        ep[0] = make_float4(e16[0],  e16[1],  e16[2],  e16[3]);
        ep[1] = make_float4(e16[4],  e16[5],  e16[6],  e16[7]);
        ep[2] = make_float4(e16[8],  e16[9],  e16[10], e16[11]);
        ep[3] = make_float4(e16[12], e16[13], e16[14], e16[15]);
    }

    // ---- GCN mixing: lanes 4s..4s+3 hold nodes 0..3 of sample s
    const int c = tid & 3;
    const float4 ar = *reinterpret_cast<const float4*>(ahat + c * 4);
    const int lbase = (tx & 63) & ~3;

    float g[32];
#pragma unroll
    for (int e = 0; e < 32; ++e) {
        float v0 = __shfl(tt[e], lbase + 0, 64);
        float v1 = __shfl(tt[e], lbase + 1, 64);
        float v2 = __shfl(tt[e], lbase + 2, 64);
        float v3 = __shfl(tt[e], lbase + 3, 64);
        float s = bg1[e];
        s = fmaf(ar.x, v0, s);
        s = fmaf(ar.y, v1, s);
        s = fmaf(ar.z, v2, s);
        s = fmaf(ar.w, v3, s);
        g[e] = fmaxf(s, 0.f);
    }

    float uu[4];
#pragma unroll
    for (int o = 0; o < 4; ++o) {
        float s = 0.f;
#pragma unroll
        for (int e = 0; e < 32; ++e) s = fmaf(g[e], Wg2[e * 4 + o], s);
        uu[o] = s;
    }

    float ov[4];
#pragma unroll
    for (int o = 0; o < 4; ++o) {
        float v0 = __shfl(uu[o], lbase + 0, 64);
        float v1 = __shfl(uu[o], lbase + 1, 64);
        float v2 = __shfl(uu[o], lbase + 2, 64);
        float v3 = __shfl(uu[o], lbase + 3, 64);
        float s = bg2[o];
        s = fmaf(ar.x, v0, s);
        s = fmaf(ar.y, v1, s);
        s = fmaf(ar.z, v2, s);
        s = fmaf(ar.w, v3, s);
        ov[o] = s;
    }
    *reinterpret_cast<float4*>(out_out + (size_t)tid * 4) =
        make_float4(ov[0], ov[1], ov[2], ov[3]);
}

// ---------------------------------------------------------------------------
extern "C" void kernel_launch(void* const* d_in, const int* in_sizes, int n_in,
                              void* d_out, int out_size, void* d_ws, size_t ws_size,
                              hipStream_t stream) {
    const float* x   = (const float*)d_in[0];
    const float* W1  = (const float*)d_in[1];
    const float* b1  = (const float*)d_in[2];
    const float* W2  = (const float*)d_in[3];
    const float* b2  = (const float*)d_in[4];
    const float* W3  = (const float*)d_in[5];
    const float* b3  = (const float*)d_in[6];
    const float* Wg1 = (const float*)d_in[7];
    const float* bg1 = (const float*)d_in[8];
    const float* Wg2 = (const float*)d_in[9];
    const float* bg2 = (const float*)d_in[10];

    unsigned int* ws_mask = (unsigned int*)d_ws;
    float* ahat = (float*)((char*)d_ws + 64);
    float* W3g  = (float*)((char*)d_ws + 256);
    float* b3g  = (float*)((char*)d_ws + 256 + 64 * 32 * 4);

    float* emb_out = (float*)d_out;
    float* out_out = emb_out + EMB_ELEMS;

    hipMemsetAsync(d_ws, 0, 4, stream);
    adj_kernel<<<NB / 256, 256, 0, stream>>>(x, ws_mask);
    ahat_kernel<<<1, 64, 0, stream>>>(ws_mask, ahat);
    prep_kernel<<<1, 256, 0, stream>>>(W3, b3, Wg1, W3g, b3g);
    mlp_gcn_kernel<<<NNODE / 256, 256, 0, stream>>>(
        x, W1, b1, W2, b2, W3, b3, ahat, W3g, b3g, Wg2, bg2, bg1,
        emb_out, out_out);
}

// Round 3
// 240.636 us; speedup vs baseline: 2.9169x; 2.5824x over previous
//
#include <hip/hip_runtime.h>

#define NB 262144
#define NNODE (NB * 4)
#define EMB_ELEMS ((size_t)NNODE * 64)

typedef __attribute__((ext_vector_type(8))) _Float16 f16x8;
typedef __attribute__((ext_vector_type(4))) float f32x4;
typedef __attribute__((ext_vector_type(4))) unsigned int u32x4;

// ---- LDS/ws weight-image layout (bytes). Strides padded to 8-f16 (16 B)
// multiples so ds_read_b128 is aligned; odd-ish dword strides spread banks.
#define OW1E  0        // [128][40] f16 : W1^T ext (k0..3=W1, k4=b1, pad 0)
#define OW2T  10240    // [64][136] f16 : W2^T  (row jo, col ji)
#define OW3T  27648    // [64][72]  f16 : W3^T  (row h,  col j)
#define OW3GT 36864    // [32][72]  f16 : (W3@Wg1)^T (row e, col j)
#define OF32  41472    // f32 section
#define IMG_BYTES 42880
// f32 section offsets (in floats)
#define FB2   0
#define FB3   64
#define FB3G  128
#define FBG1  160
#define FWG2  192      // [32][4]
#define FBG2  320
#define FAHAT 324      // [4][4]

// ---------------------------------------------------------------------------
// Kernel 1: cosine-similarity adjacency union -> 6-bit mask (f32, unchanged).
// ---------------------------------------------------------------------------
__global__ __launch_bounds__(256) void adj_kernel(const float* __restrict__ x,
                                                  unsigned int* __restrict__ mask_out) {
    __shared__ unsigned int smask;
    if (threadIdx.x == 0) smask = 0u;
    __syncthreads();
    unsigned int m = 0u;
    int s = blockIdx.x * 256 + threadIdx.x;
    if (s < NB) {
        const float* xs = x + (size_t)s * 16;
        float v[4][4], inv[4];
#pragma unroll
        for (int c = 0; c < 4; ++c) {
            float4 q = *reinterpret_cast<const float4*>(xs + c * 4);
            v[c][0] = q.x; v[c][1] = q.y; v[c][2] = q.z; v[c][3] = q.w;
            float nn = sqrtf(q.x * q.x + q.y * q.y + q.z * q.z + q.w * q.w);
            inv[c] = 1.0f / fmaxf(nn, 1e-8f);
        }
        int bit = 0;
#pragma unroll
        for (int i = 0; i < 4; ++i)
#pragma unroll
            for (int j = i + 1; j < 4; ++j) {
                float d = v[i][0]*v[j][0] + v[i][1]*v[j][1] + v[i][2]*v[j][2] + v[i][3]*v[j][3];
                if (d * inv[i] * inv[j] > 0.5f) m |= (1u << bit);
                ++bit;
            }
    }
    atomicOr(&smask, m);
    __syncthreads();
    if (threadIdx.x == 0 && smask) atomicOr(mask_out, smask);
}

// ---------------------------------------------------------------------------
// Kernel 2: build the f16 weight image + f32 biases/Ahat in workspace.
// ---------------------------------------------------------------------------
__global__ __launch_bounds__(256) void prep_kernel(
    const float* __restrict__ W1, const float* __restrict__ b1,
    const float* __restrict__ W2, const float* __restrict__ b2,
    const float* __restrict__ W3, const float* __restrict__ b3,
    const float* __restrict__ Wg1, const float* __restrict__ bg1,
    const float* __restrict__ Wg2, const float* __restrict__ bg2,
    const unsigned int* __restrict__ mask_in, char* __restrict__ img)
{
    const int t = threadIdx.x;
    _Float16* H = (_Float16*)img;
    float* F = (float*)(img + OF32);

    for (int i = t; i < 128 * 40; i += 256) {           // W1E
        int j = i / 40, kk = i % 40;
        float v = (kk < 4) ? W1[kk * 128 + j] : (kk == 4 ? b1[j] : 0.f);
        H[OW1E / 2 + i] = (_Float16)v;
    }
    for (int i = t; i < 64 * 136; i += 256) {           // W2T
        int jo = i / 136, ji = i % 136;
        H[OW2T / 2 + i] = (_Float16)(ji < 128 ? W2[ji * 64 + jo] : 0.f);
    }
    for (int i = t; i < 64 * 72; i += 256) {            // W3T
        int h = i / 72, j = i % 72;
        H[OW3T / 2 + i] = (_Float16)(j < 64 ? W3[j * 64 + h] : 0.f);
    }
    for (int i = t; i < 32 * 72; i += 256) {            // W3GT = (W3@Wg1)^T
        int e = i / 72, j = i % 72;
        float s = 0.f;
        if (j < 64)
            for (int h = 0; h < 64; ++h) s = fmaf(W3[j * 64 + h], Wg1[h * 32 + e], s);
        H[OW3GT / 2 + i] = (_Float16)s;
    }
    for (int i = t; i < 64; i += 256) F[FB2 + i] = b2[i];
    for (int i = t; i < 64; i += 256) F[FB3 + i] = b3[i];
    for (int i = t; i < 32; i += 256) {                 // b3g = b3 @ Wg1
        float s = 0.f;
        for (int h = 0; h < 64; ++h) s = fmaf(b3[h], Wg1[h * 32 + i], s);
        F[FB3G + i] = s;
    }
    for (int i = t; i < 32; i += 256) F[FBG1 + i] = bg1[i];
    for (int i = t; i < 128; i += 256) F[FWG2 + i] = Wg2[i];
    for (int i = t; i < 4; i += 256) F[FBG2 + i] = bg2[i];
    if (t == 0) {
        unsigned int m = *mask_in;
        float A[4][4];
        for (int i = 0; i < 4; ++i)
            for (int j = 0; j < 4; ++j) A[i][j] = (i == j) ? 1.f : 0.f;
        int bit = 0;
        for (int i = 0; i < 4; ++i)
            for (int j = i + 1; j < 4; ++j) {
                if ((m >> bit) & 1u) { A[i][j] = 1.f; A[j][i] = 1.f; }
                ++bit;
            }
        float dinv[4];
        for (int i = 0; i < 4; ++i)
            dinv[i] = 1.0f / sqrtf(A[i][0] + A[i][1] + A[i][2] + A[i][3]);
        for (int i = 0; i < 4; ++i)
            for (int j = 0; j < 4; ++j) F[FAHAT + i * 4 + j] = dinv[i] * A[i][j] * dinv[j];
    }
}

// ---------------------------------------------------------------------------
// helpers
// ---------------------------------------------------------------------------
__device__ __forceinline__ unsigned pkf16(float a, float b) {   // f16 pair -> u32 (RTE)
    unsigned short ha = __builtin_bit_cast(unsigned short, (_Float16)a);
    unsigned short hb = __builtin_bit_cast(unsigned short, (_Float16)b);
    return (unsigned)ha | ((unsigned)hb << 16);
}
__device__ __forceinline__ f32x4 MF(f16x8 a, f16x8 b, f32x4 c) {
    return __builtin_amdgcn_mfma_f32_16x16x32_f16(a, b, c, 0, 0, 0);
}
__device__ __forceinline__ f16x8 ldA(const _Float16* p) {
    return *(const f16x8*)p;            // 16B-aligned ds_read_b128
}
template <int M>
__device__ __forceinline__ f16x8 buildB(const unsigned (&pk)[M][4][2], int kt2, int nt,
                                        int src0, int src1, bool hiSel) {
    // B-frag elem e of lane(g,c): act[node nt*16+c][k = 8g + 2p + (e&1) + 32*kt]
    // = pk[kt2 + (g>>1)][nt][p&1] from lane (2(g&1)+(p>>1))*16 + c
    unsigned q[4];
#pragma unroll
    for (int p = 0; p < 4; ++p) {
        const int sl = (p >> 1) ? src1 : src0;
        unsigned lo = __shfl(pk[kt2][nt][p & 1], sl);
        unsigned hi = __shfl(pk[kt2 + 1][nt][p & 1], sl);
        q[p] = hiSel ? hi : lo;
    }
    u32x4 t; t.x = q[0]; t.y = q[1]; t.z = q[2]; t.w = q[3];
    return __builtin_bit_cast(f16x8, t);
}
template <int J>
__device__ __forceinline__ float qb(float v) {      // broadcast lane (base4+J) via DPP
    constexpr int ctrl = J | (J << 2) | (J << 4) | (J << 6);
    int r = __builtin_amdgcn_update_dpp(0, __builtin_bit_cast(int, v), ctrl, 0xF, 0xF, true);
    return __builtin_bit_cast(float, r);
}

// ---------------------------------------------------------------------------
// Kernel 3: fused MLP+GCN, f16 MFMA (16x16x32), transposed dataflow.
// 512 thr = 8 waves; each wave does 4 tiles of 64 nodes.
// ---------------------------------------------------------------------------
__global__ __launch_bounds__(512, 2) void mlp_gcn_mfma(
    const float* __restrict__ x, const char* __restrict__ img,
    float* __restrict__ emb_out, float* __restrict__ out_out)
{
    __shared__ char smem[IMG_BYTES];
    const int tx = threadIdx.x;
    {   // stage weight image (flat, coalesced)
        const u32x4* src = (const u32x4*)img;
        u32x4* dst = (u32x4*)smem;
        for (int i = tx; i < IMG_BYTES / 16; i += 512) dst[i] = src[i];
    }
    __syncthreads();

    const _Float16* wh = (const _Float16*)smem;
    const float* wf = (const float*)(smem + OF32);

    const int wid = tx >> 6, lane = tx & 63;
    const int g = lane >> 4, c = lane & 15;
    const bool g0 = (g == 0);
    const bool hiSel = ((g >> 1) & 1) != 0;
    const int src0 = (g & 1) * 32 + c;      // perm src lanes for B-build
    const int src1 = src0 + 16;

    // tail constants (lane-dependent, tile-invariant)
    const f32x4 arow = *(const f32x4*)(wf + FAHAT + (c & 3) * 4);
    f32x4 bg1v[2];
    bg1v[0] = *(const f32x4*)(wf + FBG1 + g * 4);
    bg1v[1] = *(const f32x4*)(wf + FBG1 + 16 + g * 4);
    const f32x4 bg2v = *(const f32x4*)(wf + FBG2);

#pragma unroll 1
    for (int it = 0; it < 4; ++it) {
        const int tile = (blockIdx.x * 8 + wid) * 4 + it;
        const size_t nbase = (size_t)tile * 64;

        // ---- x -> B-frags (bias slot k=4 gets 1.0) ----
        f32x4 xv = *(const f32x4*)(x + (nbase + lane) * 4);
        unsigned xpk01 = pkf16(xv.x, xv.y), xpk23 = pkf16(xv.z, xv.w);
        f16x8 xB[4];
#pragma unroll
        for (int nt = 0; nt < 4; ++nt) {
            int src = nt * 16 + c;
            unsigned a0 = __shfl(xpk01, src), a1 = __shfl(xpk23, src);
            u32x4 t;
            t.x = g0 ? a0 : 0u;
            t.y = g0 ? a1 : 0u;
            t.z = g0 ? 0x00003C00u : 0u;    // f16 {1.0, 0}
            t.w = 0u;
            xB[nt] = __builtin_bit_cast(f16x8, t);
        }

        // ---- L1: h1^T = W1E . xB  (bias folded) ----
        unsigned pk1[8][4][2];
#pragma unroll
        for (int mt = 0; mt < 8; ++mt) {
            f16x8 a = ldA(wh + OW1E / 2 + (mt * 16 + c) * 40 + g * 8);
            f32x4 tacc[4];
#pragma unroll
            for (int nt = 0; nt < 4; ++nt) {
                f32x4 z = {0.f, 0.f, 0.f, 0.f};
                tacc[nt] = MF(a, xB[nt], z);
            }
#pragma unroll
            for (int nt = 0; nt < 4; ++nt) {
                pk1[mt][nt][0] = pkf16(fmaxf(tacc[nt][0], 0.f), fmaxf(tacc[nt][1], 0.f));
                pk1[mt][nt][1] = pkf16(fmaxf(tacc[nt][2], 0.f), fmaxf(tacc[nt][3], 0.f));
            }
        }

        // ---- L2: h2^T = W2T . h1^T + b2 ----
        f32x4 acc2[4][4];
#pragma unroll
        for (int mt = 0; mt < 4; ++mt) {
            f32x4 bv = *(const f32x4*)(wf + FB2 + mt * 16 + g * 4);
#pragma unroll
            for (int nt = 0; nt < 4; ++nt) acc2[mt][nt] = bv;
        }
#pragma unroll
        for (int kt = 0; kt < 4; ++kt) {
            f16x8 bf[4];
#pragma unroll
            for (int nt = 0; nt < 4; ++nt) bf[nt] = buildB(pk1, 2 * kt, nt, src0, src1, hiSel);
#pragma unroll
            for (int mt = 0; mt < 4; ++mt) {
                f16x8 a = ldA(wh + OW2T / 2 + (mt * 16 + c) * 136 + kt * 32 + g * 8);
#pragma unroll
                for (int nt = 0; nt < 4; ++nt) acc2[mt][nt] = MF(a, bf[nt], acc2[mt][nt]);
            }
        }
        unsigned pk2a[4][4][2];
#pragma unroll
        for (int mt = 0; mt < 4; ++mt)
#pragma unroll
            for (int nt = 0; nt < 4; ++nt) {
                pk2a[mt][nt][0] = pkf16(fmaxf(acc2[mt][nt][0], 0.f), fmaxf(acc2[mt][nt][1], 0.f));
                pk2a[mt][nt][1] = pkf16(fmaxf(acc2[mt][nt][2], 0.f), fmaxf(acc2[mt][nt][3], 0.f));
            }

        // ---- L3: emb^T = W3T . h2^T + b3 ; tt^T = W3GT . h2^T + b3g ----
        f32x4 acc3[4][4], acc4[2][4];
#pragma unroll
        for (int mt = 0; mt < 4; ++mt) {
            f32x4 bv = *(const f32x4*)(wf + FB3 + mt * 16 + g * 4);
#pragma unroll
            for (int nt = 0; nt < 4; ++nt) acc3[mt][nt] = bv;
        }
#pragma unroll
        for (int mt = 0; mt < 2; ++mt) {
            f32x4 bv = *(const f32x4*)(wf + FB3G + mt * 16 + g * 4);
#pragma unroll
            for (int nt = 0; nt < 4; ++nt) acc4[mt][nt] = bv;
        }
#pragma unroll
        for (int kt = 0; kt < 2; ++kt) {
            f16x8 bf[4];
#pragma unroll
            for (int nt = 0; nt < 4; ++nt) bf[nt] = buildB(pk2a, 2 * kt, nt, src0, src1, hiSel);
#pragma unroll
            for (int mt = 0; mt < 4; ++mt) {
                f16x8 a = ldA(wh + OW3T / 2 + (mt * 16 + c) * 72 + kt * 32 + g * 8);
#pragma unroll
                for (int nt = 0; nt < 4; ++nt) acc3[mt][nt] = MF(a, bf[nt], acc3[mt][nt]);
            }
#pragma unroll
            for (int mt = 0; mt < 2; ++mt) {
                f16x8 a = ldA(wh + OW3GT / 2 + (mt * 16 + c) * 72 + kt * 32 + g * 8);
#pragma unroll
                for (int nt = 0; nt < 4; ++nt) acc4[mt][nt] = MF(a, bf[nt], acc4[mt][nt]);
            }
        }

        // ---- emb store: lane(g,c) frag(mt,nt) = emb[node nt*16+c][h mt*16+4g..+3]
#pragma unroll
        for (int nt = 0; nt < 4; ++nt) {
            float* ep = emb_out + (nbase + nt * 16 + c) * 64 + g * 4;
#pragma unroll
            for (int mt = 0; mt < 4; ++mt)
                *(f32x4*)(ep + mt * 16) = acc3[mt][nt];
        }

        // ---- GCN tail: per-lane over tt C-frags (sample = quad of cols) ----
        f32x4 wg2v[2][4];
#pragma unroll
        for (int m = 0; m < 2; ++m)
#pragma unroll
            for (int r = 0; r < 4; ++r)
                wg2v[m][r] = *(const f32x4*)(wf + FWG2 + (m * 16 + g * 4 + r) * 4);

#pragma unroll
        for (int nt = 0; nt < 4; ++nt) {
            float u[4] = {0.f, 0.f, 0.f, 0.f};
#pragma unroll
            for (int m = 0; m < 2; ++m)
#pragma unroll
                for (int r = 0; r < 4; ++r) {
                    float v = acc4[m][nt][r];
                    float s = bg1v[m][r];
                    s = fmaf(arow.x, qb<0>(v), s);
                    s = fmaf(arow.y, qb<1>(v), s);
                    s = fmaf(arow.z, qb<2>(v), s);
                    s = fmaf(arow.w, qb<3>(v), s);
                    s = fmaxf(s, 0.f);                      // g = relu(A.tt + bg1)
                    u[0] = fmaf(s, wg2v[m][r].x, u[0]);     // u += g . Wg2 (partial)
                    u[1] = fmaf(s, wg2v[m][r].y, u[1]);
                    u[2] = fmaf(s, wg2v[m][r].z, u[2]);
                    u[3] = fmaf(s, wg2v[m][r].w, u[3]);
                }
#pragma unroll
            for (int o = 0; o < 4; ++o) {                   // reduce e-partials over g
                u[o] += __shfl_xor(u[o], 16);
                u[o] += __shfl_xor(u[o], 32);
            }
            float ov[4];
#pragma unroll
            for (int o = 0; o < 4; ++o) {                   // out = A.u + bg2
                float s = bg2v[o];
                s = fmaf(arow.x, qb<0>(u[o]), s);
                s = fmaf(arow.y, qb<1>(u[o]), s);
                s = fmaf(arow.z, qb<2>(u[o]), s);
                s = fmaf(arow.w, qb<3>(u[o]), s);
                ov[o] = s;
            }
            if (g0) {
                f32x4 t; t.x = ov[0]; t.y = ov[1]; t.z = ov[2]; t.w = ov[3];
                *(f32x4*)(out_out + (nbase + nt * 16 + c) * 4) = t;
            }
        }
    }
}

// ---------------------------------------------------------------------------
extern "C" void kernel_launch(void* const* d_in, const int* in_sizes, int n_in,
                              void* d_out, int out_size, void* d_ws, size_t ws_size,
                              hipStream_t stream) {
    const float* x   = (const float*)d_in[0];
    const float* W1  = (const float*)d_in[1];
    const float* b1  = (const float*)d_in[2];
    const float* W2  = (const float*)d_in[3];
    const float* b2  = (const float*)d_in[4];
    const float* W3  = (const float*)d_in[5];
    const float* b3  = (const float*)d_in[6];
    const float* Wg1 = (const float*)d_in[7];
    const float* bg1 = (const float*)d_in[8];
    const float* Wg2 = (const float*)d_in[9];
    const float* bg2 = (const float*)d_in[10];

    unsigned int* mask = (unsigned int*)d_ws;
    char* img = (char*)d_ws + 256;

    float* emb_out = (float*)d_out;
    float* out_out = emb_out + EMB_ELEMS;

    hipMemsetAsync(d_ws, 0, 4, stream);
    adj_kernel<<<NB / 256, 256, 0, stream>>>(x, mask);
    prep_kernel<<<1, 256, 0, stream>>>(W1, b1, W2, b2, W3, b3, Wg1, bg1, Wg2, bg2,
                                       mask, img);
    mlp_gcn_mfma<<<512, 512, 0, stream>>>(x, img, emb_out, out_out);
}

// Round 5
// 176.774 us; speedup vs baseline: 3.9706x; 1.3613x over previous
//
#include <hip/hip_runtime.h>

#define NB 262144
#define NNODE (NB * 4)
#define EMB_ELEMS ((size_t)NNODE * 64)

typedef __attribute__((ext_vector_type(8))) _Float16 f16x8;
typedef __attribute__((ext_vector_type(4))) float f32x4;
typedef __attribute__((ext_vector_type(4))) unsigned int u32x4;

// ---- weight-image layout (bytes), strides padded to 16B multiples ----
#define OW1E  0        // [128][40] f16 : W1^T ext (k0..3=W1, k4=b1, pad 0)
#define OW2T  10240    // [64][136] f16 : W2^T  (row jo, col ji)
#define OW3T  27648    // [64][72]  f16 : W3^T  (row h,  col j)
#define OW3GT 36864    // [32][72]  f16 : (W3@Wg1)^T (row e, col j)
#define OF32  41472    // f32 section
#define IMG_BYTES 42880
// f32 section offsets (floats)
#define FB2   0
#define FB3   64
#define FB3G  128
#define FBG1  160
#define FWG2  192      // [32][4]
#define FBG2  320
#define FAHAT 324      // [4][4]

#define TRN_BYTES (4 * 4096)               // 4 waves x 4KB transpose buffers
#define SMEM_BYTES (IMG_BYTES + TRN_BYTES) // 59264 < 64KB

template <int J>
__device__ __forceinline__ float qb(float v) {      // broadcast quad-lane J (DPP)
    constexpr int ctrl = J | (J << 2) | (J << 4) | (J << 6);
    int r = __builtin_amdgcn_update_dpp(0, __builtin_bit_cast(int, v), ctrl, 0xF, 0xF, true);
    return __builtin_bit_cast(float, r);
}

// ---------------------------------------------------------------------------
// Kernel 1: adjacency union. One thread per NODE (coalesced float4 loads);
// quad lanes = one sample's 4 nodes; dots via DPP quad broadcasts.
// NOTE: all DPP broadcasts happen at FULL exec BEFORE any divergent branch —
// quad_perm from an exec-masked source lane returns 0 (bound_ctrl), which was
// R4's bug (qb<J>(inv) inside `&&` ran with lane J masked -> mask always 0).
// ---------------------------------------------------------------------------
__global__ __launch_bounds__(256) void adj_kernel(const float* __restrict__ x,
                                                  unsigned int* __restrict__ mask_out) {
    __shared__ unsigned int smask;
    if (threadIdx.x == 0) smask = 0u;
    __syncthreads();

    const int t = blockIdx.x * 256 + threadIdx.x;   // node id (grid exact)
    const int c = t & 3;
    f32x4 v = *(const f32x4*)(x + (size_t)t * 4);
    float nn = sqrtf(v.x * v.x + v.y * v.y + v.z * v.z + v.w * v.w);
    float inv = 1.0f / fmaxf(nn, 1e-8f);

    unsigned int m = 0u;
#define DOTJ(J) do {                                                            \
        const float bx = qb<J>(v.x), by = qb<J>(v.y);                           \
        const float bz = qb<J>(v.z), bw = qb<J>(v.w);                           \
        const float bi = qb<J>(inv);     /* unconditional: full exec mask */    \
        const float d = v.x * bx + v.y * by + v.z * bz + v.w * bw;              \
        if ((int)((J) != c) & (int)(d * inv * bi > 0.5f)) {                     \
            const int i_ = c < (J) ? c : (J);                                   \
            const int j_ = c < (J) ? (J) : c;                                   \
            m |= 1u << (2 * i_ + j_ - 1 - (i_ >> 1));                           \
        }                                                                       \
    } while (0)
    DOTJ(0); DOTJ(1); DOTJ(2); DOTJ(3);
#undef DOTJ

    if (m) atomicOr(&smask, m);
    __syncthreads();
    if (threadIdx.x == 0 && smask) atomicOr(mask_out, smask);
}

// ---------------------------------------------------------------------------
// Kernel 2: build f16 weight image + f32 biases/Ahat in workspace.
// ---------------------------------------------------------------------------
__global__ __launch_bounds__(256) void prep_kernel(
    const float* __restrict__ W1, const float* __restrict__ b1,
    const float* __restrict__ W2, const float* __restrict__ b2,
    const float* __restrict__ W3, const float* __restrict__ b3,
    const float* __restrict__ Wg1, const float* __restrict__ bg1,
    const float* __restrict__ Wg2, const float* __restrict__ bg2,
    const unsigned int* __restrict__ mask_in, char* __restrict__ img)
{
    const int t = threadIdx.x;
    _Float16* H = (_Float16*)img;
    float* F = (float*)(img + OF32);

    for (int i = t; i < 128 * 40; i += 256) {           // W1E
        int j = i / 40, kk = i % 40;
        float v = (kk < 4) ? W1[kk * 128 + j] : (kk == 4 ? b1[j] : 0.f);
        H[OW1E / 2 + i] = (_Float16)v;
    }
    for (int i = t; i < 64 * 136; i += 256) {           // W2T
        int jo = i / 136, ji = i % 136;
        H[OW2T / 2 + i] = (_Float16)(ji < 128 ? W2[ji * 64 + jo] : 0.f);
    }
    for (int i = t; i < 64 * 72; i += 256) {            // W3T
        int h = i / 72, j = i % 72;
        H[OW3T / 2 + i] = (_Float16)(j < 64 ? W3[j * 64 + h] : 0.f);
    }
    for (int i = t; i < 32 * 72; i += 256) {            // W3GT = (W3@Wg1)^T
        int e = i / 72, j = i % 72;
        float s = 0.f;
        if (j < 64)
            for (int h = 0; h < 64; ++h) s = fmaf(W3[j * 64 + h], Wg1[h * 32 + e], s);
        H[OW3GT / 2 + i] = (_Float16)s;
    }
    for (int i = t; i < 64; i += 256) F[FB2 + i] = b2[i];
    for (int i = t; i < 64; i += 256) F[FB3 + i] = b3[i];
    for (int i = t; i < 32; i += 256) {                 // b3g = b3 @ Wg1
        float s = 0.f;
        for (int h = 0; h < 64; ++h) s = fmaf(b3[h], Wg1[h * 32 + i], s);
        F[FB3G + i] = s;
    }
    for (int i = t; i < 32; i += 256) F[FBG1 + i] = bg1[i];
    for (int i = t; i < 128; i += 256) F[FWG2 + i] = Wg2[i];
    for (int i = t; i < 4; i += 256) F[FBG2 + i] = bg2[i];
    if (t == 0) {
        unsigned int m = *mask_in;
        float A[4][4];
        for (int i = 0; i < 4; ++i)
            for (int j = 0; j < 4; ++j) A[i][j] = (i == j) ? 1.f : 0.f;
        int bit = 0;
        for (int i = 0; i < 4; ++i)
            for (int j = i + 1; j < 4; ++j) {
                if ((m >> bit) & 1u) { A[i][j] = 1.f; A[j][i] = 1.f; }
                ++bit;
            }
        float dinv[4];
        for (int i = 0; i < 4; ++i)
            dinv[i] = 1.0f / sqrtf(A[i][0] + A[i][1] + A[i][2] + A[i][3]);
        for (int i = 0; i < 4; ++i)
            for (int j = 0; j < 4; ++j) F[FAHAT + i * 4 + j] = dinv[i] * A[i][j] * dinv[j];
    }
}

// ---------------------------------------------------------------------------
// helpers
// ---------------------------------------------------------------------------
__device__ __forceinline__ unsigned pkf16(float a, float b) {
    unsigned short ha = __builtin_bit_cast(unsigned short, (_Float16)a);
    unsigned short hb = __builtin_bit_cast(unsigned short, (_Float16)b);
    return (unsigned)ha | ((unsigned)hb << 16);
}
__device__ __forceinline__ f32x4 MF(f16x8 a, f16x8 b, f32x4 c) {
    return __builtin_amdgcn_mfma_f32_16x16x32_f16(a, b, c, 0, 0, 0);
}
__device__ __forceinline__ f16x8 ldA(const _Float16* p) {
    return *(const f16x8*)p;            // 16B-aligned ds_read_b128
}
template <int M>
__device__ __forceinline__ f16x8 buildB(const unsigned (&pk)[M][4][2], int kt2, int nt,
                                        int src0, int src1, bool hiSel) {
    unsigned q[4];
#pragma unroll
    for (int p = 0; p < 4; ++p) {
        const int sl = (p >> 1) ? src1 : src0;
        unsigned lo = __shfl(pk[kt2][nt][p & 1], sl);
        unsigned hi = __shfl(pk[kt2 + 1][nt][p & 1], sl);
        q[p] = hiSel ? hi : lo;
    }
    u32x4 t; t.x = q[0]; t.y = q[1]; t.z = q[2]; t.w = q[3];
    return __builtin_bit_cast(f16x8, t);
}

// ---------------------------------------------------------------------------
// Kernel 3: fused MLP+GCN, f16 MFMA. 256 thr = 4 waves, 4 tiles of 64 nodes
// per wave. emb stored via per-wave LDS transpose -> 1KB-contiguous
// nontemporal stores (full 128B lines per instruction => no L2 RFO).
// ---------------------------------------------------------------------------
__global__ __launch_bounds__(256, 2) void mlp_gcn_mfma(
    const float* __restrict__ x, const char* __restrict__ img,
    float* __restrict__ emb_out, float* __restrict__ out_out)
{
    __shared__ u32x4 smem4[SMEM_BYTES / 16];
    char* smem = (char*)smem4;
    const int tx = threadIdx.x;
    {   // stage weight image (flat, coalesced)
        const u32x4* src = (const u32x4*)img;
        u32x4* dst = (u32x4*)smem;
        for (int i = tx; i < IMG_BYTES / 16; i += 256) dst[i] = src[i];
    }
    __syncthreads();

    const _Float16* wh = (const _Float16*)smem;
    const float* wf = (const float*)(smem + OF32);

    const int wid = tx >> 6, lane = tx & 63;
    const int g = lane >> 4, c = lane & 15;
    const bool g0 = (g == 0);
    const bool hiSel = ((g >> 1) & 1) != 0;
    const int src0 = (g & 1) * 32 + c;
    const int src1 = src0 + 16;

    float* tb = (float*)(smem + IMG_BYTES) + wid * 1024;   // 4KB/wave transpose buf

    // tail constants
    const f32x4 arow = *(const f32x4*)(wf + FAHAT + (c & 3) * 4);
    f32x4 bg1v[2];
    bg1v[0] = *(const f32x4*)(wf + FBG1 + g * 4);
    bg1v[1] = *(const f32x4*)(wf + FBG1 + 16 + g * 4);
    const f32x4 bg2v = *(const f32x4*)(wf + FBG2);
    f32x4 wg2v[2][4];
#pragma unroll
    for (int m = 0; m < 2; ++m)
#pragma unroll
        for (int r = 0; r < 4; ++r)
            wg2v[m][r] = *(const f32x4*)(wf + FWG2 + (m * 16 + g * 4 + r) * 4);

    const size_t nbase0 = ((size_t)blockIdx.x * 4 + wid) * 256;
    f32x4 xv = *(const f32x4*)(x + (nbase0 + lane) * 4);   // prefetch it=0

#pragma unroll 1
    for (int it = 0; it < 4; ++it) {
        const size_t nbase = nbase0 + (size_t)it * 64;
        // prefetch next tile's x
        const size_t pn = (it < 3) ? (nbase + 64) : nbase;
        f32x4 xnext = *(const f32x4*)(x + (pn + lane) * 4);

        // ---- x -> B-frags (bias slot k=4 gets 1.0) ----
        unsigned xpk01 = pkf16(xv.x, xv.y), xpk23 = pkf16(xv.z, xv.w);
        f16x8 xB[4];
#pragma unroll
        for (int nt = 0; nt < 4; ++nt) {
            int src = nt * 16 + c;
            unsigned a0 = __shfl(xpk01, src), a1 = __shfl(xpk23, src);
            u32x4 t;
            t.x = g0 ? a0 : 0u;
            t.y = g0 ? a1 : 0u;
            t.z = g0 ? 0x00003C00u : 0u;    // f16 {1.0, 0}
            t.w = 0u;
            xB[nt] = __builtin_bit_cast(f16x8, t);
        }

        // ---- L1: h1^T = W1E . xB ----
        unsigned pk1[8][4][2];
#pragma unroll
        for (int mt = 0; mt < 8; ++mt) {
            f16x8 a = ldA(wh + OW1E / 2 + (mt * 16 + c) * 40 + g * 8);
            f32x4 tacc[4];
#pragma unroll
            for (int nt = 0; nt < 4; ++nt) {
                f32x4 z = {0.f, 0.f, 0.f, 0.f};
                tacc[nt] = MF(a, xB[nt], z);
            }
#pragma unroll
            for (int nt = 0; nt < 4; ++nt) {
                pk1[mt][nt][0] = pkf16(fmaxf(tacc[nt][0], 0.f), fmaxf(tacc[nt][1], 0.f));
                pk1[mt][nt][1] = pkf16(fmaxf(tacc[nt][2], 0.f), fmaxf(tacc[nt][3], 0.f));
            }
        }

        // ---- L2: h2^T = W2T . h1^T + b2 ----
        f32x4 acc2[4][4];
#pragma unroll
        for (int mt = 0; mt < 4; ++mt) {
            f32x4 bv = *(const f32x4*)(wf + FB2 + mt * 16 + g * 4);
#pragma unroll
            for (int nt = 0; nt < 4; ++nt) acc2[mt][nt] = bv;
        }
#pragma unroll
        for (int kt = 0; kt < 4; ++kt) {
            f16x8 bf[4];
#pragma unroll
            for (int nt = 0; nt < 4; ++nt) bf[nt] = buildB(pk1, 2 * kt, nt, src0, src1, hiSel);
#pragma unroll
            for (int mt = 0; mt < 4; ++mt) {
                f16x8 a = ldA(wh + OW2T / 2 + (mt * 16 + c) * 136 + kt * 32 + g * 8);
#pragma unroll
                for (int nt = 0; nt < 4; ++nt) acc2[mt][nt] = MF(a, bf[nt], acc2[mt][nt]);
            }
        }
        unsigned pk2a[4][4][2];
#pragma unroll
        for (int mt = 0; mt < 4; ++mt)
#pragma unroll
            for (int nt = 0; nt < 4; ++nt) {
                pk2a[mt][nt][0] = pkf16(fmaxf(acc2[mt][nt][0], 0.f), fmaxf(acc2[mt][nt][1], 0.f));
                pk2a[mt][nt][1] = pkf16(fmaxf(acc2[mt][nt][2], 0.f), fmaxf(acc2[mt][nt][3], 0.f));
            }

        // ---- L3: emb^T = W3T . h2^T + b3 ; tt^T = W3GT . h2^T + b3g ----
        f32x4 acc3[4][4], acc4[2][4];
#pragma unroll
        for (int mt = 0; mt < 4; ++mt) {
            f32x4 bv = *(const f32x4*)(wf + FB3 + mt * 16 + g * 4);
#pragma unroll
            for (int nt = 0; nt < 4; ++nt) acc3[mt][nt] = bv;
        }
#pragma unroll
        for (int mt = 0; mt < 2; ++mt) {
            f32x4 bv = *(const f32x4*)(wf + FB3G + mt * 16 + g * 4);
#pragma unroll
            for (int nt = 0; nt < 4; ++nt) acc4[mt][nt] = bv;
        }
#pragma unroll
        for (int kt = 0; kt < 2; ++kt) {
            f16x8 bf[4];
#pragma unroll
            for (int nt = 0; nt < 4; ++nt) bf[nt] = buildB(pk2a, 2 * kt, nt, src0, src1, hiSel);
#pragma unroll
            for (int mt = 0; mt < 4; ++mt) {
                f16x8 a = ldA(wh + OW3T / 2 + (mt * 16 + c) * 72 + kt * 32 + g * 8);
#pragma unroll
                for (int nt = 0; nt < 4; ++nt) acc3[mt][nt] = MF(a, bf[nt], acc3[mt][nt]);
            }
#pragma unroll
            for (int mt = 0; mt < 2; ++mt) {
                f16x8 a = ldA(wh + OW3GT / 2 + (mt * 16 + c) * 72 + kt * 32 + g * 8);
#pragma unroll
                for (int nt = 0; nt < 4; ++nt) acc4[mt][nt] = MF(a, bf[nt], acc4[mt][nt]);
            }
        }

        // ---- emb store via per-wave LDS transpose ----
#pragma unroll
        for (int nt = 0; nt < 4; ++nt) {
#pragma unroll
            for (int mt = 0; mt < 4; ++mt) {
                int sl = (mt * 4 + g) ^ (c & 7);
                *(f32x4*)(tb + c * 64 + sl * 4) = acc3[mt][nt];
            }
            float* gp = emb_out + (nbase + nt * 16) * 64;
#pragma unroll
            for (int s = 0; s < 4; ++s) {
                int row = s * 4 + g;
                int sl = c ^ (row & 7);
                f32x4 q = *(const f32x4*)(tb + row * 64 + sl * 4);
                __builtin_nontemporal_store(q, (f32x4*)(gp + s * 256 + lane * 4));
            }
        }

        // ---- GCN tail (all qb/DPP calls unconditional, full exec) ----
#pragma unroll
        for (int nt = 0; nt < 4; ++nt) {
            float u[4] = {0.f, 0.f, 0.f, 0.f};
#pragma unroll
            for (int m = 0; m < 2; ++m)
#pragma unroll
                for (int r = 0; r < 4; ++r) {
                    float v = acc4[m][nt][r];
                    float s = bg1v[m][r];
                    s = fmaf(arow.x, qb<0>(v), s);
                    s = fmaf(arow.y, qb<1>(v), s);
                    s = fmaf(arow.z, qb<2>(v), s);
                    s = fmaf(arow.w, qb<3>(v), s);
                    s = fmaxf(s, 0.f);
                    u[0] = fmaf(s, wg2v[m][r].x, u[0]);
                    u[1] = fmaf(s, wg2v[m][r].y, u[1]);
                    u[2] = fmaf(s, wg2v[m][r].z, u[2]);
                    u[3] = fmaf(s, wg2v[m][r].w, u[3]);
                }
#pragma unroll
            for (int o = 0; o < 4; ++o) {
                u[o] += __shfl_xor(u[o], 16);
                u[o] += __shfl_xor(u[o], 32);
            }
            float ov[4];
#pragma unroll
            for (int o = 0; o < 4; ++o) {
                float s = bg2v[o];
                s = fmaf(arow.x, qb<0>(u[o]), s);
                s = fmaf(arow.y, qb<1>(u[o]), s);
                s = fmaf(arow.z, qb<2>(u[o]), s);
                s = fmaf(arow.w, qb<3>(u[o]), s);
                ov[o] = s;
            }
            if (g0) {
                f32x4 t; t.x = ov[0]; t.y = ov[1]; t.z = ov[2]; t.w = ov[3];
                __builtin_nontemporal_store(t, (f32x4*)(out_out + (nbase + nt * 16 + c) * 4));
            }
        }

        xv = xnext;
    }
}

// ---------------------------------------------------------------------------
extern "C" void kernel_launch(void* const* d_in, const int* in_sizes, int n_in,
                              void* d_out, int out_size, void* d_ws, size_t ws_size,
                              hipStream_t stream) {
    const float* x   = (const float*)d_in[0];
    const float* W1  = (const float*)d_in[1];
    const float* b1  = (const float*)d_in[2];
    const float* W2  = (const float*)d_in[3];
    const float* b2  = (const float*)d_in[4];
    const float* W3  = (const float*)d_in[5];
    const float* b3  = (const float*)d_in[6];
    const float* Wg1 = (const float*)d_in[7];
    const float* bg1 = (const float*)d_in[8];
    const float* Wg2 = (const float*)d_in[9];
    const float* bg2 = (const float*)d_in[10];

    unsigned int* mask = (unsigned int*)d_ws;
    char* img = (char*)d_ws + 256;

    float* emb_out = (float*)d_out;
    float* out_out = emb_out + EMB_ELEMS;

    hipMemsetAsync(d_ws, 0, 4, stream);
    adj_kernel<<<NNODE / 256, 256, 0, stream>>>(x, mask);
    prep_kernel<<<1, 256, 0, stream>>>(W1, b1, W2, b2, W3, b3, Wg1, bg1, Wg2, bg2,
                                       mask, img);
    mlp_gcn_mfma<<<NNODE / 1024, 256, 0, stream>>>(x, img, emb_out, out_out);
}